// Round 3
// baseline (550.660 us; speedup 1.0000x reference)
//
#include <hip/hip_runtime.h>

// DiffusionConvolution: out = X + M @ X,
//   M = th10*Wp1 + th11*WTp1 + th20*Wp2 + th21*WTp2   (Wp0 = WTp0 = I folded
//   into self_scale = 1 + th00 + th01).
//
// R8 = R7's barrier-free row-per-wave streaming with the load granularity
// fixed:
//  - R7 (b32 matrix loads, 256 B/instr, 16 instr/step) ran at 1.8 TB/s:
//    per-CU miss-queue entries, not waves, capped bytes-in-flight.
//  - Now lane l owns k = 4l..4l+3 -> each matrix load is ONE dwordx4
//    (1 KB/wave-instr, 4 instr/step), depth-2 prefetch: 8 KB in flight
//    per wave, 16 waves/CU -> 128 KB/CU >> 9 KB latency-BW product.
//  - X is stored TRANSPOSED in LDS (x_ldsT[16][1024] per 1024-k phase,
//    64 KB): per feature f one ds_read_b128 covers the lane's 4 k's; the
//    wave reads a contiguous 1 KB span = full-BW LDS access, no swizzle
//    needed. 4 phases, 2 barriers each = 8 barriers total, none in the
//    inner loop.
//  - Dropped __builtin_nontemporal_load: every nt variant capped at
//    <=2.7 TB/s; the 6.3 TB/s ubench is plain float4 loads.
//  - Epilogue: 64-lane butterfly reduce; lane 0 writes self_scale*X[r]+acc.
//    One kernel, no atomics, no init pass.
// Roofline: 268 MB @ ~6.3 TB/s ~= 43 us for this kernel.

constexpr int N  = 4096;
constexpr int F  = 16;
constexpr int TPB     = 512;     // 8 waves per block
constexpr int RPB     = 8;       // rows per block (1 per wave)
constexpr int PHASE_K = 1024;    // X rows resident per LDS phase (64 KB)

// Load one 256-k step of the 4 matrix streams: one float4 per matrix.
// Component j of B* holds k = K0 + 4*lane + j.
#define PF(B0, B1, B2, B3, K0) do {                                         \
    const size_t o_ = rowb + (size_t)(K0) + (size_t)(lane << 2);            \
    B0 = *(const float4*)(Wp1  + o_);                                       \
    B1 = *(const float4*)(WTp1 + o_);                                       \
    B2 = *(const float4*)(Wp2  + o_);                                       \
    B3 = *(const float4*)(WTp2 + o_);                                       \
} while (0)

// Consume one 256-k step held in B0..B3 against X^T in LDS.
#define COMP(B0, B1, B2, B3, K0) do {                                       \
    float4 c_;                                                              \
    c_.x = th10*B0.x + th11*B1.x + th20*B2.x + th21*B3.x;                   \
    c_.y = th10*B0.y + th11*B1.y + th20*B2.y + th21*B3.y;                   \
    c_.z = th10*B0.z + th11*B1.z + th20*B2.z + th21*B3.z;                   \
    c_.w = th10*B0.w + th11*B1.w + th20*B2.w + th21*B3.w;                   \
    const int krel_ = ((K0) & (PHASE_K - 1)) + (lane << 2);                 \
    _Pragma("unroll")                                                       \
    for (int f = 0; f < F; ++f) {                                           \
        const float4 xk = *(const float4*)&x_ldsT[f * PHASE_K + krel_];     \
        acc[f] = fmaf(c_.x, xk.x, fmaf(c_.y, xk.y,                          \
                 fmaf(c_.z, xk.z, fmaf(c_.w, xk.w, acc[f]))));              \
    }                                                                       \
} while (0)

__global__ __launch_bounds__(TPB) void diffconv_kernel(
    const float* __restrict__ X,      // [N, F]
    const float* __restrict__ theta,  // [3, 2]
    const float* __restrict__ Wp,     // [3, N, N]
    const float* __restrict__ WTp,    // [3, N, N]
    float* __restrict__ out)          // [N, F]
{
    __shared__ float x_ldsT[F * PHASE_K];   // 64 KB, X transposed: [f][k]

    const int tid  = threadIdx.x;
    const int lane = tid & 63;
    const int wave = tid >> 6;
    const int r    = blockIdx.x * RPB + wave;

    const float th00 = theta[0], th01 = theta[1];
    const float th10 = theta[2], th11 = theta[3];
    const float th20 = theta[4], th21 = theta[5];

    const float* __restrict__ Wp1  = Wp  + (size_t)N * N;
    const float* __restrict__ Wp2  = Wp  + 2 * (size_t)N * N;
    const float* __restrict__ WTp1 = WTp + (size_t)N * N;
    const float* __restrict__ WTp2 = WTp + 2 * (size_t)N * N;

    const size_t rowb = (size_t)r * N;

    float acc[F];
#pragma unroll
    for (int f = 0; f < F; ++f) acc[f] = 0.0f;

    float4 a0, a1, a2, a3;   // pipeline buffer A (one 256-k step)
    float4 b0, b1, b2, b3;   // pipeline buffer B

    // Fill the depth-2 pipeline (overlaps with phase-0 staging).
    PF(a0, a1, a2, a3, 0);
    PF(b0, b1, b2, b3, 256);

    for (int p = 0; p < 4; ++p) {
        __syncthreads();   // all waves done reading previous phase
        // Stage phase p: X rows [p*1024, p*1024+1024) -> transposed LDS.
#pragma unroll
        for (int h = 0; h < 2; ++h) {
            const int krel = tid + h * 512;
            const float4* src =
                (const float4*)(X + (size_t)(p * PHASE_K + krel) * F);
            const float4 v0 = src[0], v1 = src[1], v2 = src[2], v3 = src[3];
            x_ldsT[ 0 * PHASE_K + krel] = v0.x;
            x_ldsT[ 1 * PHASE_K + krel] = v0.y;
            x_ldsT[ 2 * PHASE_K + krel] = v0.z;
            x_ldsT[ 3 * PHASE_K + krel] = v0.w;
            x_ldsT[ 4 * PHASE_K + krel] = v1.x;
            x_ldsT[ 5 * PHASE_K + krel] = v1.y;
            x_ldsT[ 6 * PHASE_K + krel] = v1.z;
            x_ldsT[ 7 * PHASE_K + krel] = v1.w;
            x_ldsT[ 8 * PHASE_K + krel] = v2.x;
            x_ldsT[ 9 * PHASE_K + krel] = v2.y;
            x_ldsT[10 * PHASE_K + krel] = v2.z;
            x_ldsT[11 * PHASE_K + krel] = v2.w;
            x_ldsT[12 * PHASE_K + krel] = v3.x;
            x_ldsT[13 * PHASE_K + krel] = v3.y;
            x_ldsT[14 * PHASE_K + krel] = v3.z;
            x_ldsT[15 * PHASE_K + krel] = v3.w;
        }
        __syncthreads();

        const int k0 = p * PHASE_K;
        // 4 steps of 256 k; prefetch runs 2 steps ahead of consumption.
        COMP(a0, a1, a2, a3, k0);        PF(a0, a1, a2, a3, k0 + 512);
        COMP(b0, b1, b2, b3, k0 + 256);  PF(b0, b1, b2, b3, k0 + 768);
        COMP(a0, a1, a2, a3, k0 + 512);
        if (p < 3) PF(a0, a1, a2, a3, k0 + 1024);   // next phase
        COMP(b0, b1, b2, b3, k0 + 768);
        if (p < 3) PF(b0, b1, b2, b3, k0 + 1280);   // next phase
    }

    // Butterfly-reduce the per-lane k-partials across the 64 lanes.
#pragma unroll
    for (int mask = 1; mask < 64; mask <<= 1)
#pragma unroll
        for (int f = 0; f < F; ++f)
            acc[f] += __shfl_xor(acc[f], mask, 64);

    if (lane == 0) {
        const float self_scale = 1.0f + th00 + th01;
        const float4* xp = (const float4*)(X + (size_t)r * F);
        float4*       op = (float4*)(out + (size_t)r * F);
#pragma unroll
        for (int q = 0; q < 4; ++q) {
            const float4 xv = xp[q];
            float4 ov;
            ov.x = self_scale * xv.x + acc[4*q+0];
            ov.y = self_scale * xv.y + acc[4*q+1];
            ov.z = self_scale * xv.z + acc[4*q+2];
            ov.w = self_scale * xv.w + acc[4*q+3];
            op[q] = ov;
        }
    }
}

extern "C" void kernel_launch(void* const* d_in, const int* in_sizes, int n_in,
                              void* d_out, int out_size, void* d_ws, size_t ws_size,
                              hipStream_t stream) {
    const float* X     = (const float*)d_in[0];
    const float* theta = (const float*)d_in[1];
    const float* Wp    = (const float*)d_in[2];
    const float* WTp   = (const float*)d_in[3];
    float* out = (float*)d_out;

    diffconv_kernel<<<N / RPB, TPB, 0, stream>>>(X, theta, Wp, WTp, out);
}

// Round 5
// 535.359 us; speedup vs baseline: 1.0286x; 1.0286x over previous
//
#include <hip/hip_runtime.h>

// DiffusionConvolution: out = X + M @ X,
//   M = th10*Wp1 + th11*WTp1 + th20*Wp2 + th21*WTp2   (Wp0 = WTp0 = I folded
//   into self_scale = 1 + th00 + th01).
//
// R10 = R9 resubmitted verbatim (R9 bench died in the container broker, no
// counters returned; no information to act on).
// R9 = R8 with nontemporal restored on the 4 matrix streams (ONE change).
//  - R8 (plain loads) moved 1.07 GB for a 268 MB problem: the single-use
//    matrix stream allocated in L2/L3, evicting ~256 MB of dirty poison-fill
//    lines (-> 606 MB WRITE) and thrashing block-shared X out of L2
//    (-> +172 MB FETCH). nt loads mark the stream no-allocate: dirty L3
//    stays put, X stays L2-resident.
//  - Keeps R8's wins: dwordx4 matrix loads (1 KB/wave-instr), depth-2
//    register pipeline (8 KB in flight/wave), transposed-X LDS
//    (x_ldsT[16][1024], contiguous 1 KB wave reads, 0 bank conflicts
//    measured), zero main-loop barriers (8 per block total).
//  - Epilogue: butterfly reduce, lane 0 writes self_scale*X[r]+acc.
//    One kernel, no atomics, no init pass.
// Roofline: 268 MB @ ~6.6 TB/s ~= 41 us for this kernel.

constexpr int N  = 4096;
constexpr int F  = 16;
constexpr int TPB     = 512;     // 8 waves per block
constexpr int RPB     = 8;       // rows per block (1 per wave)
constexpr int PHASE_K = 1024;    // X rows resident per LDS phase (64 KB)

typedef float floatx4 __attribute__((ext_vector_type(4)));

__device__ __forceinline__ float4 nt_load4(const float* p) {
    floatx4 v = __builtin_nontemporal_load((const floatx4*)p);
    return make_float4(v.x, v.y, v.z, v.w);
}

// Load one 256-k step of the 4 matrix streams: one nt dwordx4 per matrix.
// Component j of B* holds k = K0 + 4*lane + j.
#define PF(B0, B1, B2, B3, K0) do {                                         \
    const size_t o_ = rowb + (size_t)(K0) + (size_t)(lane << 2);            \
    B0 = nt_load4(Wp1  + o_);                                               \
    B1 = nt_load4(WTp1 + o_);                                               \
    B2 = nt_load4(Wp2  + o_);                                               \
    B3 = nt_load4(WTp2 + o_);                                               \
} while (0)

// Consume one 256-k step held in B0..B3 against X^T in LDS.
#define COMP(B0, B1, B2, B3, K0) do {                                       \
    float4 c_;                                                              \
    c_.x = th10*B0.x + th11*B1.x + th20*B2.x + th21*B3.x;                   \
    c_.y = th10*B0.y + th11*B1.y + th20*B2.y + th21*B3.y;                   \
    c_.z = th10*B0.z + th11*B1.z + th20*B2.z + th21*B3.z;                   \
    c_.w = th10*B0.w + th11*B1.w + th20*B2.w + th21*B3.w;                   \
    const int krel_ = ((K0) & (PHASE_K - 1)) + (lane << 2);                 \
    _Pragma("unroll")                                                       \
    for (int f = 0; f < F; ++f) {                                           \
        const float4 xk = *(const float4*)&x_ldsT[f * PHASE_K + krel_];     \
        acc[f] = fmaf(c_.x, xk.x, fmaf(c_.y, xk.y,                          \
                 fmaf(c_.z, xk.z, fmaf(c_.w, xk.w, acc[f]))));              \
    }                                                                       \
} while (0)

__global__ __launch_bounds__(TPB) void diffconv_kernel(
    const float* __restrict__ X,      // [N, F]
    const float* __restrict__ theta,  // [3, 2]
    const float* __restrict__ Wp,     // [3, N, N]
    const float* __restrict__ WTp,    // [3, N, N]
    float* __restrict__ out)          // [N, F]
{
    __shared__ float x_ldsT[F * PHASE_K];   // 64 KB, X transposed: [f][k]

    const int tid  = threadIdx.x;
    const int lane = tid & 63;
    const int wave = tid >> 6;
    const int r    = blockIdx.x * RPB + wave;

    const float th00 = theta[0], th01 = theta[1];
    const float th10 = theta[2], th11 = theta[3];
    const float th20 = theta[4], th21 = theta[5];

    const float* __restrict__ Wp1  = Wp  + (size_t)N * N;
    const float* __restrict__ Wp2  = Wp  + 2 * (size_t)N * N;
    const float* __restrict__ WTp1 = WTp + (size_t)N * N;
    const float* __restrict__ WTp2 = WTp + 2 * (size_t)N * N;

    const size_t rowb = (size_t)r * N;

    float acc[F];
#pragma unroll
    for (int f = 0; f < F; ++f) acc[f] = 0.0f;

    float4 a0, a1, a2, a3;   // pipeline buffer A (one 256-k step)
    float4 b0, b1, b2, b3;   // pipeline buffer B

    // Fill the depth-2 pipeline (overlaps with phase-0 staging).
    PF(a0, a1, a2, a3, 0);
    PF(b0, b1, b2, b3, 256);

    for (int p = 0; p < 4; ++p) {
        __syncthreads();   // all waves done reading previous phase
        // Stage phase p: X rows [p*1024, p*1024+1024) -> transposed LDS.
#pragma unroll
        for (int h = 0; h < 2; ++h) {
            const int krel = tid + h * 512;
            const float4* src =
                (const float4*)(X + (size_t)(p * PHASE_K + krel) * F);
            const float4 v0 = src[0], v1 = src[1], v2 = src[2], v3 = src[3];
            x_ldsT[ 0 * PHASE_K + krel] = v0.x;
            x_ldsT[ 1 * PHASE_K + krel] = v0.y;
            x_ldsT[ 2 * PHASE_K + krel] = v0.z;
            x_ldsT[ 3 * PHASE_K + krel] = v0.w;
            x_ldsT[ 4 * PHASE_K + krel] = v1.x;
            x_ldsT[ 5 * PHASE_K + krel] = v1.y;
            x_ldsT[ 6 * PHASE_K + krel] = v1.z;
            x_ldsT[ 7 * PHASE_K + krel] = v1.w;
            x_ldsT[ 8 * PHASE_K + krel] = v2.x;
            x_ldsT[ 9 * PHASE_K + krel] = v2.y;
            x_ldsT[10 * PHASE_K + krel] = v2.z;
            x_ldsT[11 * PHASE_K + krel] = v2.w;
            x_ldsT[12 * PHASE_K + krel] = v3.x;
            x_ldsT[13 * PHASE_K + krel] = v3.y;
            x_ldsT[14 * PHASE_K + krel] = v3.z;
            x_ldsT[15 * PHASE_K + krel] = v3.w;
        }
        __syncthreads();

        const int k0 = p * PHASE_K;
        // 4 steps of 256 k; prefetch runs 2 steps ahead of consumption.
        COMP(a0, a1, a2, a3, k0);        PF(a0, a1, a2, a3, k0 + 512);
        COMP(b0, b1, b2, b3, k0 + 256);  PF(b0, b1, b2, b3, k0 + 768);
        COMP(a0, a1, a2, a3, k0 + 512);
        if (p < 3) PF(a0, a1, a2, a3, k0 + 1024);   // next phase
        COMP(b0, b1, b2, b3, k0 + 768);
        if (p < 3) PF(b0, b1, b2, b3, k0 + 1280);   // next phase
    }

    // Butterfly-reduce the per-lane k-partials across the 64 lanes.
#pragma unroll
    for (int mask = 1; mask < 64; mask <<= 1)
#pragma unroll
        for (int f = 0; f < F; ++f)
            acc[f] += __shfl_xor(acc[f], mask, 64);

    if (lane == 0) {
        const float self_scale = 1.0f + th00 + th01;
        const float4* xp = (const float4*)(X + (size_t)r * F);
        float4*       op = (float4*)(out + (size_t)r * F);
#pragma unroll
        for (int q = 0; q < 4; ++q) {
            const float4 xv = xp[q];
            float4 ov;
            ov.x = self_scale * xv.x + acc[4*q+0];
            ov.y = self_scale * xv.y + acc[4*q+1];
            ov.z = self_scale * xv.z + acc[4*q+2];
            ov.w = self_scale * xv.w + acc[4*q+3];
            op[q] = ov;
        }
    }
}

extern "C" void kernel_launch(void* const* d_in, const int* in_sizes, int n_in,
                              void* d_out, int out_size, void* d_ws, size_t ws_size,
                              hipStream_t stream) {
    const float* X     = (const float*)d_in[0];
    const float* theta = (const float*)d_in[1];
    const float* Wp    = (const float*)d_in[2];
    const float* WTp   = (const float*)d_in[3];
    float* out = (float*)d_out;

    diffconv_kernel<<<N / RPB, TPB, 0, stream>>>(X, theta, Wp, WTp, out);
}